// Round 7
// baseline (20.731 us; speedup 1.0000x reference)
//
#include <hip/hip_runtime.h>
#include <math.h>

// Problem constants (match reference setup_inputs)
#define BB 32
#define LL 1024
#define PP 8
#define DD 256
#define MARGIN_F 0.01f
// total = B * P * (L - P) = 32 * 8 * 1016
#define TOTAL_PAIRS 260096.0f
#define NBLK 512    // 16 blocks per split, 64 rows per block, 512 threads

// Single compute node. Per block:
//   - q in registers (4 float4 per lane; each 16-lane group spans D)
//   - hoisted loads: 2 streamed rows + (groups 0..7) positive row
//   - positive sims -> LDS, hinge folded in registers, block reduce
//   - publish partial via relaxed agent-scope atomicExch (atomic->atomic
//     transfer needs NO fence); opaque data-dep chains the exchange's
//     completion into the ticket atomicAdd (hardware-ordered, no wbl2)
//   - ticket winner (t == NBLK-1): all 512 partials re-read via relaxed
//     agent atomic loads in FIXED order -> deterministic sum -> out[0].
// Ticket is zeroed every call by a 4-byte hipMemsetAsync node -> robust
// against the 0xAA workspace poison and any initial garbage.
__global__ __launch_bounds__(512) void main_kernel(const float* __restrict__ sent,
                                                   const float* __restrict__ query,
                                                   const int* __restrict__ pos_idx,
                                                   float* __restrict__ partial,
                                                   unsigned* __restrict__ ticket,
                                                   float* __restrict__ out) {
    const int blk   = blockIdx.x;
    const int b     = blk >> 4;   // split (16 blocks per split)
    const int chunk = blk & 15;   // 64-row slice within split
    const int tid   = threadIdx.x;
    const int g     = tid >> 4;   // 16-lane group (0..31)
    const int seg   = tid & 15;

    const float* qr = query + (size_t)b * DD;

    // ---- issue q loads ----
    float4 qv[4];
#pragma unroll
    for (int k = 0; k < 4; ++k)
        qv[k] = *reinterpret_cast<const float4*>(qr + (k * 16 + seg) * 4);

    // ---- issue both streamed-row loads (held in registers) ----
    const int l0 = chunk * 64 + g;
    const int l1 = chunk * 64 + 32 + g;
    const float* x0 = sent + ((size_t)(b * LL + l0)) * DD;
    const float* x1 = sent + ((size_t)(b * LL + l1)) * DD;
    float4 xv0[4], xv1[4];
#pragma unroll
    for (int k = 0; k < 4; ++k) {
        xv0[k] = *reinterpret_cast<const float4*>(x0 + (k * 16 + seg) * 4);
        xv1[k] = *reinterpret_cast<const float4*>(x1 + (k * 16 + seg) * 4);
    }

    // ---- issue positive-row loads (groups 0..7) ----
    __shared__ float ltpos[PP];
    __shared__ int   lpid[PP];
    float4 pv[4];
    int prow = 0;
    if (g < PP) {
        prow = pos_idx[b * PP + g];
#pragma unroll
        for (int k = 0; k < 4; ++k)
            pv[k] = *reinterpret_cast<const float4*>(sent + ((size_t)(b * LL + prow)) * DD + (k * 16 + seg) * 4);
    }

    // ---- ||q||: register-only, identical tree per group -> bit-identical ----
    float nq = 0.f;
#pragma unroll
    for (int k = 0; k < 4; ++k)
        nq += qv[k].x * qv[k].x + qv[k].y * qv[k].y + qv[k].z * qv[k].z + qv[k].w * qv[k].w;
#pragma unroll
    for (int off = 8; off > 0; off >>= 1) nq += __shfl_xor(nq, off, 16);
    const float qiv = 1.0f / fmaxf(sqrtf(nq), 1e-12f);

    // ---- positive sims ----
    if (g < PP) {
        float dot = 0.f, nx = 0.f;
#pragma unroll
        for (int k = 0; k < 4; ++k) {
            dot += pv[k].x * qv[k].x + pv[k].y * qv[k].y + pv[k].z * qv[k].z + pv[k].w * qv[k].w;
            nx  += pv[k].x * pv[k].x + pv[k].y * pv[k].y + pv[k].z * pv[k].z + pv[k].w * pv[k].w;
        }
#pragma unroll
        for (int off = 8; off > 0; off >>= 1) {
            dot += __shfl_xor(dot, off, 16);
            nx  += __shfl_xor(nx,  off, 16);
        }
        if (seg == 0) {
            ltpos[g] = (dot * qiv) / fmaxf(sqrtf(nx), 1e-12f) - MARGIN_F;
            lpid[g]  = prow;
        }
    }
    __syncthreads();

    float tpos[PP];
    int   pidr[PP];
#pragma unroll
    for (int p = 0; p < PP; ++p) { tpos[p] = ltpos[p]; pidr[p] = lpid[p]; }

    // ---- consume the register-held rows ----
    float d0 = 0.f, n0 = 0.f, d1 = 0.f, n1 = 0.f;
#pragma unroll
    for (int k = 0; k < 4; ++k) {
        d0 += xv0[k].x * qv[k].x + xv0[k].y * qv[k].y + xv0[k].z * qv[k].z + xv0[k].w * qv[k].w;
        n0 += xv0[k].x * xv0[k].x + xv0[k].y * xv0[k].y + xv0[k].z * xv0[k].z + xv0[k].w * xv0[k].w;
        d1 += xv1[k].x * qv[k].x + xv1[k].y * qv[k].y + xv1[k].z * qv[k].z + xv1[k].w * qv[k].w;
        n1 += xv1[k].x * xv1[k].x + xv1[k].y * xv1[k].y + xv1[k].z * xv1[k].z + xv1[k].w * xv1[k].w;
    }
#pragma unroll
    for (int off = 8; off > 0; off >>= 1) {
        d0 += __shfl_xor(d0, off, 16);
        n0 += __shfl_xor(n0, off, 16);
        d1 += __shfl_xor(d1, off, 16);
        n1 += __shfl_xor(n1, off, 16);
    }

    float acc = 0.f;
    if (seg == 0) {
        const float s0 = (d0 * qiv) / fmaxf(sqrtf(n0), 1e-12f);
        const float s1 = (d1 * qiv) / fmaxf(sqrtf(n1), 1e-12f);
        bool p0 = false, p1 = false;
#pragma unroll
        for (int p = 0; p < PP; ++p) {
            p0 |= (l0 == pidr[p]);
            p1 |= (l1 == pidr[p]);
        }
        if (!p0) {
#pragma unroll
            for (int p = 0; p < PP; ++p) acc += fmaxf(s0 - tpos[p], 0.f);
        }
        if (!p1) {
#pragma unroll
            for (int p = 0; p < PP; ++p) acc += fmaxf(s1 - tpos[p], 0.f);
        }
    }

    // ---- block reduce (8 waves) ----
#pragma unroll
    for (int off = 32; off > 0; off >>= 1) acc += __shfl_xor(acc, off, 64);
    __shared__ float wsum[8];
    if ((tid & 63) == 0) wsum[tid >> 6] = acc;
    __syncthreads();

    // ---- publish partial + ticket (fence-free, hardware-ordered) ----
    __shared__ int lastflag;
    if (tid == 0) {
        float p = 0.f;
#pragma unroll
        for (int w = 0; w < 8; ++w) p += wsum[w];
        const float old = __hip_atomic_exchange(&partial[blk], p,
                                                __ATOMIC_RELAXED, __HIP_MEMORY_SCOPE_AGENT);
        // opaque zero derived from the exchange's RETURN VALUE: forces the
        // exchange to be complete at the coherence point before the ticket
        // add can issue (true data dependency, no fence, no wbl2).
        unsigned oz;
        asm volatile("v_and_b32 %0, 0, %1" : "=v"(oz) : "v"(__float_as_uint(old)));
        const unsigned t = __hip_atomic_fetch_add(ticket, 1u + oz,
                                                  __ATOMIC_RELAXED, __HIP_MEMORY_SCOPE_AGENT);
        lastflag = (t == (unsigned)(NBLK - 1));
    }
    __syncthreads();
    if (!lastflag) return;

    // ---- winner: fixed-order deterministic sum of all 512 partials ----
    float s = __hip_atomic_load(&partial[tid], __ATOMIC_RELAXED, __HIP_MEMORY_SCOPE_AGENT);
#pragma unroll
    for (int off = 32; off > 0; off >>= 1) s += __shfl_xor(s, off, 64);
    __shared__ float fsum[8];
    if ((tid & 63) == 0) fsum[tid >> 6] = s;
    __syncthreads();
    if (tid == 0) {
        float total = 0.f;
#pragma unroll
        for (int w = 0; w < 8; ++w) total += fsum[w];
        out[0] = total / TOTAL_PAIRS;
    }
}

extern "C" void kernel_launch(void* const* d_in, const int* in_sizes, int n_in,
                              void* d_out, int out_size, void* d_ws, size_t ws_size,
                              hipStream_t stream) {
    const float* sent  = (const float*)d_in[0];   // [B, L, D] f32
    const float* query = (const float*)d_in[1];   // [B, D]    f32
    const int*   pidx  = (const int*)d_in[2];     // [B, P]
    float* out = (float*)d_out;

    unsigned* ticket  = (unsigned*)d_ws;          // byte 0..3
    float*    partial = (float*)d_ws + 64;        // byte 256.., NBLK floats

    // Cheap memset node: guarantees ticket==0 at every call (robust against
    // the one-time 0xAA workspace poison and any initial garbage).
    hipMemsetAsync(d_ws, 0, 4, stream);
    main_kernel<<<NBLK, 512, 0, stream>>>(sent, query, pidx, partial, ticket, out);
}

// Round 8
// 13.247 us; speedup vs baseline: 1.5650x; 1.5650x over previous
//
#include <hip/hip_runtime.h>
#include <math.h>

// Problem constants (match reference setup_inputs)
#define BB 32
#define LL 1024
#define PP 8
#define DD 256
#define MARGIN_F 0.01f
// total = B * P * (L - P) = 32 * 8 * 1016
#define TOTAL_PAIRS 260096.0f
#define NBLK 512    // 16 blocks per split, 64 rows per block (4 per 16-lane group)

// K1: all loads issued up-front (q, 4 streamed rows, positive row for
// groups 0..7), then math. Positive sims -> LDS once per block; hinge folded
// in registers; block-reduce; ONE plain store. No atomics, no fences.
__global__ __launch_bounds__(256) void main_kernel(const float* __restrict__ sent,
                                                   const float* __restrict__ query,
                                                   const int* __restrict__ pos_idx,
                                                   float* __restrict__ partial) {
    const int blk   = blockIdx.x;
    const int b     = blk >> 4;   // split (16 blocks per split)
    const int chunk = blk & 15;   // 64-row slice within split
    const int tid   = threadIdx.x;
    const int g     = tid >> 4;   // 16-lane group (0..15)
    const int seg   = tid & 15;

    const float* qr = query + (size_t)b * DD;

    // ---- issue q loads ----
    float4 qv[4];
#pragma unroll
    for (int k = 0; k < 4; ++k)
        qv[k] = *reinterpret_cast<const float4*>(qr + (k * 16 + seg) * 4);

    // ---- issue all 4 streamed-row loads (held in registers) ----
    int lr[4];
    float4 xv[4][4];
#pragma unroll
    for (int r = 0; r < 4; ++r) {
        lr[r] = chunk * 64 + r * 16 + g;
        const float* xr = sent + ((size_t)(b * LL + lr[r])) * DD;
#pragma unroll
        for (int k = 0; k < 4; ++k)
            xv[r][k] = *reinterpret_cast<const float4*>(xr + (k * 16 + seg) * 4);
    }

    // ---- issue positive-row loads (groups 0..7) ----
    __shared__ float ltpos[PP];
    __shared__ int   lpid[PP];
    float4 pv[4];
    int prow = 0;
    if (g < PP) {
        prow = pos_idx[b * PP + g];
#pragma unroll
        for (int k = 0; k < 4; ++k)
            pv[k] = *reinterpret_cast<const float4*>(sent + ((size_t)(b * LL + prow)) * DD + (k * 16 + seg) * 4);
    }

    // ---- ||q||: register-only, identical tree per group -> bit-identical ----
    float nq = 0.f;
#pragma unroll
    for (int k = 0; k < 4; ++k)
        nq += qv[k].x * qv[k].x + qv[k].y * qv[k].y + qv[k].z * qv[k].z + qv[k].w * qv[k].w;
#pragma unroll
    for (int off = 8; off > 0; off >>= 1) nq += __shfl_xor(nq, off, 16);
    const float qiv = 1.0f / fmaxf(sqrtf(nq), 1e-12f);

    // ---- positive sims ----
    if (g < PP) {
        float dot = 0.f, nx = 0.f;
#pragma unroll
        for (int k = 0; k < 4; ++k) {
            dot += pv[k].x * qv[k].x + pv[k].y * qv[k].y + pv[k].z * qv[k].z + pv[k].w * qv[k].w;
            nx  += pv[k].x * pv[k].x + pv[k].y * pv[k].y + pv[k].z * pv[k].z + pv[k].w * pv[k].w;
        }
#pragma unroll
        for (int off = 8; off > 0; off >>= 1) {
            dot += __shfl_xor(dot, off, 16);
            nx  += __shfl_xor(nx,  off, 16);
        }
        if (seg == 0) {
            ltpos[g] = (dot * qiv) / fmaxf(sqrtf(nx), 1e-12f) - MARGIN_F;
            lpid[g]  = prow;
        }
    }
    __syncthreads();

    float tpos[PP];
    int   pidr[PP];
#pragma unroll
    for (int p = 0; p < PP; ++p) { tpos[p] = ltpos[p]; pidr[p] = lpid[p]; }

    // ---- consume the 4 register-held rows ----
    float d[4], n[4];
#pragma unroll
    for (int r = 0; r < 4; ++r) {
        d[r] = 0.f; n[r] = 0.f;
#pragma unroll
        for (int k = 0; k < 4; ++k) {
            d[r] += xv[r][k].x * qv[k].x + xv[r][k].y * qv[k].y + xv[r][k].z * qv[k].z + xv[r][k].w * qv[k].w;
            n[r] += xv[r][k].x * xv[r][k].x + xv[r][k].y * xv[r][k].y + xv[r][k].z * xv[r][k].z + xv[r][k].w * xv[r][k].w;
        }
    }
#pragma unroll
    for (int off = 8; off > 0; off >>= 1) {
#pragma unroll
        for (int r = 0; r < 4; ++r) {
            d[r] += __shfl_xor(d[r], off, 16);
            n[r] += __shfl_xor(n[r], off, 16);
        }
    }

    float acc = 0.f;
    if (seg == 0) {
#pragma unroll
        for (int r = 0; r < 4; ++r) {
            const float s = (d[r] * qiv) / fmaxf(sqrtf(n[r]), 1e-12f);
            bool is_pos = false;
#pragma unroll
            for (int p = 0; p < PP; ++p) is_pos |= (lr[r] == pidr[p]);
            if (!is_pos) {
#pragma unroll
                for (int p = 0; p < PP; ++p) acc += fmaxf(s - tpos[p], 0.f);
            }
        }
    }

    // ---- block reduce, one store ----
#pragma unroll
    for (int off = 32; off > 0; off >>= 1) acc += __shfl_xor(acc, off, 64);
    __shared__ float wsum[4];
    if ((tid & 63) == 0) wsum[tid >> 6] = acc;
    __syncthreads();
    if (tid == 0) partial[blk] = wsum[0] + wsum[1] + wsum[2] + wsum[3];
}

// K2: single wave, no LDS, no syncthreads. 64 threads x 8 partials (2 float4,
// independent loads), fixed-order reduce, scale, write.
__global__ __launch_bounds__(64) void final_kernel(const float* __restrict__ partial,
                                                   float* __restrict__ out) {
    const int tid = threadIdx.x;
    const float4 a = *reinterpret_cast<const float4*>(partial + tid * 8);
    const float4 c = *reinterpret_cast<const float4*>(partial + tid * 8 + 4);
    float s = (a.x + a.y + a.z + a.w) + (c.x + c.y + c.z + c.w);
#pragma unroll
    for (int off = 32; off > 0; off >>= 1) s += __shfl_xor(s, off, 64);
    if (tid == 0) out[0] = s / TOTAL_PAIRS;
}

extern "C" void kernel_launch(void* const* d_in, const int* in_sizes, int n_in,
                              void* d_out, int out_size, void* d_ws, size_t ws_size,
                              hipStream_t stream) {
    const float* sent  = (const float*)d_in[0];   // [B, L, D] f32
    const float* query = (const float*)d_in[1];   // [B, D]    f32
    const int*   pidx  = (const int*)d_in[2];     // [B, P]
    float* out = (float*)d_out;
    float* partial = (float*)d_ws;                // NBLK floats

    main_kernel <<<NBLK, 256, 0, stream>>>(sent, query, pidx, partial);
    final_kernel<<<1, 64, 0, stream>>>(partial, out);
}